// Round 11
// baseline (255.399 us; speedup 1.0000x reference)
//
#include <hip/hip_runtime.h>
#include <math.h>

#define BB 4
#define CC 256
#define NHEAD 4
#define DH 32
#define NN 4096
#define HID 128

typedef _Float16 f16;
typedef _Float16 f16x8 __attribute__((ext_vector_type(8)));
typedef _Float16 f16x4 __attribute__((ext_vector_type(4)));
typedef float f32x4 __attribute__((ext_vector_type(4)));

// q-hat prescaled by 10*log2(e); softmax shift folded into MFMA C-init.
#define QPRESCALE 14.42695041f
#define NSHIFT 14.42695041f

#if __has_builtin(__builtin_amdgcn_exp2f)
#define EXP2F(x) __builtin_amdgcn_exp2f(x)
#else
#define EXP2F(x) __expf((x)*0.6931471805599453f)
#endif

__device__ __forceinline__ f16x8 cvt8(const float* p) {
    float4 a = *(const float4*)p;
    float4 b = *(const float4*)(p + 4);
    f16x8 r;
    r[0] = (f16)a.x; r[1] = (f16)a.y; r[2] = (f16)a.z; r[3] = (f16)a.w;
    r[4] = (f16)b.x; r[5] = (f16)b.y; r[6] = (f16)b.z; r[7] = (f16)b.w;
    return r;
}

// ---------------- kernel 1: fused qkv GEMM + l2norm + layout ----------------
__global__ __launch_bounds__(256) void qkv_fused(const float* __restrict__ x,
                                                 const float* __restrict__ wq,
                                                 f16* __restrict__ qh,
                                                 f16* __restrict__ kh,
                                                 f16* __restrict__ vh) {
    int wave = threadIdx.x >> 6, lane = threadIdx.x & 63;
    int quad = lane >> 4, col = lane & 15;
    int b = blockIdx.z;
    int o0 = blockIdx.y * 32;                 // one head (or v-head) slice
    int i0 = blockIdx.x * 128 + wave * 32;    // wave's 32-i tile
    const float* xb = x + (size_t)b * CC * NN;

    f32x4 c[2][2];  // [mt][nt]
#pragma unroll
    for (int mt = 0; mt < 2; mt++)
#pragma unroll
        for (int nt = 0; nt < 2; nt++) c[mt][nt] = f32x4{0.f, 0.f, 0.f, 0.f};

#pragma unroll
    for (int k0 = 0; k0 < CC; k0 += 32) {
        f16x8 a[2];
#pragma unroll
        for (int mt = 0; mt < 2; mt++)
            a[mt] = cvt8(wq + (size_t)(o0 + mt * 16 + col) * CC + k0 + quad * 8);
#pragma unroll
        for (int nt = 0; nt < 2; nt++) {
            const float* xc = xb + (size_t)(k0 + quad * 8) * NN + i0 + nt * 16 + col;
            f16x8 bf;
#pragma unroll
            for (int j = 0; j < 8; j++) bf[j] = (f16)xc[(size_t)j * NN];
            c[0][nt] = __builtin_amdgcn_mfma_f32_16x16x32_f16(a[0], bf, c[0][nt], 0, 0, 0);
            c[1][nt] = __builtin_amdgcn_mfma_f32_16x16x32_f16(a[1], bf, c[1][nt], 0, 0, 0);
        }
    }

    if (o0 < 256) {
        int isQ = (o0 < 128);
        int h = (isQ ? o0 : (o0 - 128)) >> 5;
        f16* dst = isQ ? qh : kh;
        float pre = isQ ? QPRESCALE : 1.0f;
#pragma unroll
        for (int nt = 0; nt < 2; nt++) {
            float ss = 0.f;
#pragma unroll
            for (int mt = 0; mt < 2; mt++)
#pragma unroll
                for (int r = 0; r < 4; r++) ss = fmaf(c[mt][nt][r], c[mt][nt][r], ss);
            ss += __shfl_xor(ss, 16);
            ss += __shfl_xor(ss, 32);
            float inv = pre / fmaxf(sqrtf(ss), 1e-12f);
            size_t row = ((size_t)(b * 4 + h) * NN + i0 + nt * 16 + col) * 32;
#pragma unroll
            for (int mt = 0; mt < 2; mt++) {
                f16x4 st;
#pragma unroll
                for (int r = 0; r < 4; r++) st[r] = (f16)(c[mt][nt][r] * inv);
                *(f16x4*)(dst + row + mt * 16 + quad * 4) = st;
            }
        }
    } else {
        int h = (o0 - 256) >> 5;
#pragma unroll
        for (int nt = 0; nt < 2; nt++) {
            int i = i0 + nt * 16 + col;
#pragma unroll
            for (int mt = 0; mt < 2; mt++)
#pragma unroll
                for (int r = 0; r < 4; r++)
                    vh[((size_t)(b * 4 + h) * 32 + mt * 16 + quad * 4 + r) * NN + i] =
                        (f16)c[mt][nt][r];
        }
    }
}

// ---------------- kernel 2: MFMA flash attention ----------------
// 32 q-rows/block, 4-wave key split, (256,4) no-spill cap (R9 lesson).
// NEW (R11): 4-slot KV pipeline — loads issued 3-4 chunks (~550+ cyc of
// work) ahead of use, independent register buffers so the compiler emits
// fine-grained vmcnt waits per chunk. Grid/mapping unchanged (R10-proven:
// FETCH 6 MB).
struct KV32 {
    f16x8 k0, k1;
    f16x4 v0n0, v0n1, v1n0, v1n1;
};

__device__ __forceinline__ KV32 load_kv(const f16* __restrict__ kb,
                                        const f16* __restrict__ vb,
                                        int jb, int col, int quad) {
    KV32 f;
    f.k0 = *(const f16x8*)(kb + (size_t)(jb + col) * 32 + quad * 8);
    f.k1 = *(const f16x8*)(kb + (size_t)(jb + 16 + col) * 32 + quad * 8);
    f.v0n0 = *(const f16x4*)(vb + (size_t)col * NN + jb + quad * 4);
    f.v0n1 = *(const f16x4*)(vb + (size_t)(16 + col) * NN + jb + quad * 4);
    f.v1n0 = *(const f16x4*)(vb + (size_t)col * NN + jb + 16 + quad * 4);
    f.v1n1 = *(const f16x4*)(vb + (size_t)(16 + col) * NN + jb + 16 + quad * 4);
    return f;
}

__device__ __forceinline__ f16x4 expblk(f32x4 s, float& lacc) {
    float p0 = EXP2F(s[0]), p1 = EXP2F(s[1]);
    float p2 = EXP2F(s[2]), p3 = EXP2F(s[3]);
    lacc += (p0 + p1) + (p2 + p3);
    f16x4 r;
    r[0] = (f16)p0; r[1] = (f16)p1; r[2] = (f16)p2; r[3] = (f16)p3;
    return r;
}

__device__ __forceinline__ void compute32(const KV32& f, f16x8 qB0, f16x8 qB1,
                                          f32x4& o00, f32x4& o01,
                                          f32x4& o10, f32x4& o11,
                                          float& l0, float& l1) {
    const f32x4 zs = {-NSHIFT, -NSHIFT, -NSHIFT, -NSHIFT};
    f32x4 s00 = __builtin_amdgcn_mfma_f32_16x16x32_f16(f.k0, qB0, zs, 0, 0, 0);
    f32x4 s10 = __builtin_amdgcn_mfma_f32_16x16x32_f16(f.k0, qB1, zs, 0, 0, 0);
    f32x4 s01 = __builtin_amdgcn_mfma_f32_16x16x32_f16(f.k1, qB0, zs, 0, 0, 0);
    f32x4 s11 = __builtin_amdgcn_mfma_f32_16x16x32_f16(f.k1, qB1, zs, 0, 0, 0);
    f16x4 p00 = expblk(s00, l0);
    f16x4 p10 = expblk(s10, l1);
    f16x4 p01 = expblk(s01, l0);
    f16x4 p11 = expblk(s11, l1);
    o00 = __builtin_amdgcn_mfma_f32_16x16x16f16(p00, f.v0n0, o00, 0, 0, 0);
    o01 = __builtin_amdgcn_mfma_f32_16x16x16f16(p00, f.v0n1, o01, 0, 0, 0);
    o10 = __builtin_amdgcn_mfma_f32_16x16x16f16(p10, f.v0n0, o10, 0, 0, 0);
    o11 = __builtin_amdgcn_mfma_f32_16x16x16f16(p10, f.v0n1, o11, 0, 0, 0);
    o00 = __builtin_amdgcn_mfma_f32_16x16x16f16(p01, f.v1n0, o00, 0, 0, 0);
    o01 = __builtin_amdgcn_mfma_f32_16x16x16f16(p01, f.v1n1, o01, 0, 0, 0);
    o10 = __builtin_amdgcn_mfma_f32_16x16x16f16(p11, f.v1n0, o10, 0, 0, 0);
    o11 = __builtin_amdgcn_mfma_f32_16x16x16f16(p11, f.v1n1, o11, 0, 0, 0);
}

__global__ __launch_bounds__(256, 4) void attn_mfma(const f16* __restrict__ qh,
                                                    const f16* __restrict__ kh,
                                                    const f16* __restrict__ vh,
                                                    f16* __restrict__ att16) {
    __shared__ float olds[4][32][33];
    __shared__ float llds[4][32];
    int t = threadIdx.x;
    int wave = t >> 6, lane = t & 63;
    int quad = lane >> 4, col = lane & 15;

    // 2048 blocks; bid&7 round-robin grouping (R10: FETCH 6 MB, keep as-is).
    int bid = blockIdx.x;
    int xcd = bid & 7;
    int slot = bid >> 3;             // 0..255
    int bh = xcd * 2 + (slot >> 7);  // 0..15
    int i0 = (slot & 127) * 32;

    const f16* qb = qh + (size_t)bh * NN * 32;
    const f16* kb = kh + (size_t)bh * NN * 32;
    const f16* vb = vh + (size_t)bh * 32 * NN;

    f16x8 qB0 = *(const f16x8*)(qb + (size_t)(i0 + col) * 32 + quad * 8);
    f16x8 qB1 = *(const f16x8*)(qb + (size_t)(i0 + 16 + col) * 32 + quad * 8);

    f32x4 o00 = {0.f, 0.f, 0.f, 0.f}, o01 = o00, o10 = o00, o11 = o00;
    float l0 = 0.f, l1 = 0.f;

    int jbeg = wave * 1024, jend = jbeg + 1024;
    // 4-slot pipeline: 128 keys in flight ahead of compute.
    KV32 b0 = load_kv(kb, vb, jbeg +  0, col, quad);
    KV32 b1 = load_kv(kb, vb, jbeg + 32, col, quad);
    KV32 b2 = load_kv(kb, vb, jbeg + 64, col, quad);
    KV32 b3 = load_kv(kb, vb, jbeg + 96, col, quad);
    for (int j = jbeg; j < jend; j += 128) {
        int p0 = (j + 128 < jend) ? j + 128 : jbeg;
        int p1 = (j + 160 < jend) ? j + 160 : jbeg;
        int p2 = (j + 192 < jend) ? j + 192 : jbeg;
        int p3 = (j + 224 < jend) ? j + 224 : jbeg;
        compute32(b0, qB0, qB1, o00, o01, o10, o11, l0, l1);
        b0 = load_kv(kb, vb, p0, col, quad);
        compute32(b1, qB0, qB1, o00, o01, o10, o11, l0, l1);
        b1 = load_kv(kb, vb, p1, col, quad);
        compute32(b2, qB0, qB1, o00, o01, o10, o11, l0, l1);
        b2 = load_kv(kb, vb, p2, col, quad);
        compute32(b3, qB0, qB1, o00, o01, o10, o11, l0, l1);
        b3 = load_kv(kb, vb, p3, col, quad);
    }

    // wave-local l reduction (keys split across quads)
    l0 += __shfl_xor(l0, 16); l0 += __shfl_xor(l0, 32);
    l1 += __shfl_xor(l1, 16); l1 += __shfl_xor(l1, 32);

#pragma unroll
    for (int r = 0; r < 4; r++) {
        olds[wave][quad * 4 + r][col]           = o00[r];
        olds[wave][quad * 4 + r][16 + col]      = o01[r];
        olds[wave][16 + quad * 4 + r][col]      = o10[r];
        olds[wave][16 + quad * 4 + r][16 + col] = o11[r];
    }
    if (quad == 0) {
        llds[wave][col] = l0;
        llds[wave][16 + col] = l1;
    }
    __syncthreads();

    // combine 4 key-chunks, normalize, store f16 i-major att16[b][i][h*32+dh]
    int ii = t >> 3;
    int g = t & 7;
    float sum[4];
#pragma unroll
    for (int e = 0; e < 4; e++)
        sum[e] = olds[0][ii][g * 4 + e] + olds[1][ii][g * 4 + e] +
                 olds[2][ii][g * 4 + e] + olds[3][ii][g * 4 + e];
    float l = llds[0][ii] + llds[1][ii] + llds[2][ii] + llds[3][ii];
    float inv = 1.0f / l;
    f16x4 o4;
#pragma unroll
    for (int e = 0; e < 4; e++) o4[e] = (f16)(sum[e] * inv);
    int b = bh >> 2, h = bh & 3;
    *(f16x4*)(att16 + ((size_t)b * NN + i0 + ii) * HID + h * 32 + g * 4) = o4;
}

// ---------------- kernel 3: output projection (MFMA) + bias ----------------
__global__ __launch_bounds__(256) void out_mfma(const f16* __restrict__ att16,
                                                const float* __restrict__ wo,
                                                const float* __restrict__ bo,
                                                float* __restrict__ out) {
    int wave = threadIdx.x >> 6, lane = threadIdx.x & 63;
    int quad = lane >> 4, col = lane & 15;
    int b = blockIdx.z;
    int i0 = (blockIdx.x * 4 + wave) * 32;
    int o0 = blockIdx.y * 64;
    const f16* ab = att16 + (size_t)b * NN * HID;

    const f32x4 z = {0.f, 0.f, 0.f, 0.f};
    f32x4 c[2][4];
#pragma unroll
    for (int it = 0; it < 2; it++)
#pragma unroll
        for (int ot = 0; ot < 4; ot++) c[it][ot] = z;

#pragma unroll
    for (int k0 = 0; k0 < HID; k0 += 32) {
        f16x8 a0 = *(const f16x8*)(ab + (size_t)(i0 + col) * HID + k0 + quad * 8);
        f16x8 a1 = *(const f16x8*)(ab + (size_t)(i0 + 16 + col) * HID + k0 + quad * 8);
#pragma unroll
        for (int ot = 0; ot < 4; ot++) {
            f16x8 bf = cvt8(wo + (size_t)(o0 + ot * 16 + col) * HID + k0 + quad * 8);
            c[0][ot] = __builtin_amdgcn_mfma_f32_16x16x32_f16(a0, bf, c[0][ot], 0, 0, 0);
            c[1][ot] = __builtin_amdgcn_mfma_f32_16x16x32_f16(a1, bf, c[1][ot], 0, 0, 0);
        }
    }

#pragma unroll
    for (int it = 0; it < 2; it++)
#pragma unroll
        for (int ot = 0; ot < 4; ot++) {
            int o = o0 + ot * 16 + col;
            float bias = bo[o];
            int i = i0 + it * 16 + quad * 4;
            float4 st = {c[it][ot][0] + bias, c[it][ot][1] + bias,
                         c[it][ot][2] + bias, c[it][ot][3] + bias};
            *(float4*)(out + ((size_t)b * CC + o) * NN + i) = st;
        }
}

extern "C" void kernel_launch(void* const* d_in, const int* in_sizes, int n_in,
                              void* d_out, int out_size, void* d_ws, size_t ws_size,
                              hipStream_t stream) {
    const float* x     = (const float*)d_in[0];
    const float* w_qkv = (const float*)d_in[1];
    const float* w_out = (const float*)d_in[2];
    const float* b_out = (const float*)d_in[3];
    float* out = (float*)d_out;

    char* ws = (char*)d_ws;
    f16* qh    = (f16*)(ws);                        // 4 MB
    f16* kh    = (f16*)(ws + (4u << 20));           // 4 MB
    f16* vh    = (f16*)(ws + (8u << 20));           // 4 MB
    f16* att16 = (f16*)(ws + (12u << 20));          // 4 MB

    qkv_fused<<<dim3(NN / 128, 384 / 32, BB), 256, 0, stream>>>(x, w_qkv, qh, kh, vh);
    attn_mfma<<<dim3(2048), 256, 0, stream>>>(qh, kh, vh, att16);
    out_mfma<<<dim3(NN / 128, CC / 64, BB), 256, 0, stream>>>(att16, w_out, b_out, out);
}

// Round 12
// 167.763 us; speedup vs baseline: 1.5224x; 1.5224x over previous
//
#include <hip/hip_runtime.h>
#include <math.h>

#define BB 4
#define CC 256
#define NHEAD 4
#define DH 32
#define NN 4096
#define HID 128

typedef _Float16 f16;
typedef _Float16 f16x8 __attribute__((ext_vector_type(8)));
typedef _Float16 f16x4 __attribute__((ext_vector_type(4)));
typedef float f32x4 __attribute__((ext_vector_type(4)));

#define QPRESCALE 14.42695041f
#define NSHIFT 14.42695041f

#if __has_builtin(__builtin_amdgcn_exp2f)
#define EXP2F(x) __builtin_amdgcn_exp2f(x)
#else
#define EXP2F(x) __expf((x)*0.6931471805599453f)
#endif

__device__ __forceinline__ f16x8 cvt8(const float* p) {
    float4 a = *(const float4*)p;
    float4 b = *(const float4*)(p + 4);
    f16x8 r;
    r[0] = (f16)a.x; r[1] = (f16)a.y; r[2] = (f16)a.z; r[3] = (f16)a.w;
    r[4] = (f16)b.x; r[5] = (f16)b.y; r[6] = (f16)b.z; r[7] = (f16)b.w;
    return r;
}

// ---------------- kernel 1: fused qkv GEMM + l2norm + layout ----------------
// 64-o block tile (x re-read 6x instead of 12x). Wave: 64 o x 32 i.
// C layout: col = i (n, 2nd operand), quad*4+r = o (m, 1st operand).
__global__ __launch_bounds__(256) void qkv_fused(const float* __restrict__ x,
                                                 const float* __restrict__ wq,
                                                 f16* __restrict__ qh,
                                                 f16* __restrict__ kh,
                                                 f16* __restrict__ vh) {
    int wave = threadIdx.x >> 6, lane = threadIdx.x & 63;
    int quad = lane >> 4, col = lane & 15;
    int b = blockIdx.z;
    int o0 = blockIdx.y * 64;                 // 2 heads per block tile
    int i0 = blockIdx.x * 128 + wave * 32;
    const float* xb = x + (size_t)b * CC * NN;

    f32x4 c[4][2];  // [mt][nt]
#pragma unroll
    for (int mt = 0; mt < 4; mt++)
#pragma unroll
        for (int nt = 0; nt < 2; nt++) c[mt][nt] = f32x4{0.f, 0.f, 0.f, 0.f};

#pragma unroll
    for (int k0 = 0; k0 < CC; k0 += 32) {
        f16x8 a[4];
#pragma unroll
        for (int mt = 0; mt < 4; mt++)
            a[mt] = cvt8(wq + (size_t)(o0 + mt * 16 + col) * CC + k0 + quad * 8);
#pragma unroll
        for (int nt = 0; nt < 2; nt++) {
            const float* xc = xb + (size_t)(k0 + quad * 8) * NN + i0 + nt * 16 + col;
            f16x8 bf;
#pragma unroll
            for (int j = 0; j < 8; j++) bf[j] = (f16)xc[(size_t)j * NN];
#pragma unroll
            for (int mt = 0; mt < 4; mt++)
                c[mt][nt] = __builtin_amdgcn_mfma_f32_16x16x32_f16(a[mt], bf, c[mt][nt], 0, 0, 0);
        }
    }

    if (o0 < 256) {
        int isQ = (o0 < 128);
        int obase = isQ ? o0 : (o0 - 128);
        f16* dst = isQ ? qh : kh;
        float pre = isQ ? QPRESCALE : 1.0f;
#pragma unroll
        for (int nt = 0; nt < 2; nt++) {
#pragma unroll
            for (int hh = 0; hh < 2; hh++) {  // two heads: mt {0,1} and {2,3}
                float ss = 0.f;
#pragma unroll
                for (int m2 = 0; m2 < 2; m2++)
#pragma unroll
                    for (int r = 0; r < 4; r++) {
                        float v = c[hh * 2 + m2][nt][r];
                        ss = fmaf(v, v, ss);
                    }
                ss += __shfl_xor(ss, 16);
                ss += __shfl_xor(ss, 32);
                float inv = pre / fmaxf(sqrtf(ss), 1e-12f);
                int h = (obase + hh * 32) >> 5;
                size_t row = ((size_t)(b * 4 + h) * NN + i0 + nt * 16 + col) * 32;
#pragma unroll
                for (int m2 = 0; m2 < 2; m2++) {
                    f16x4 st;
#pragma unroll
                    for (int r = 0; r < 4; r++) st[r] = (f16)(c[hh * 2 + m2][nt][r] * inv);
                    *(f16x4*)(dst + row + m2 * 16 + quad * 4) = st;
                }
            }
        }
    } else {
        int o2 = o0 - 256;  // 0 or 64
#pragma unroll
        for (int nt = 0; nt < 2; nt++) {
            int i = i0 + nt * 16 + col;
#pragma unroll
            for (int mt = 0; mt < 4; mt++) {
                int h = (o2 + mt * 16) >> 5;
                int d = (mt & 1) * 16 + quad * 4;
#pragma unroll
                for (int r = 0; r < 4; r++)
                    vh[((size_t)(b * 4 + h) * 32 + d + r) * NN + i] = (f16)c[mt][nt][r];
            }
        }
    }
}

// ---------------- kernel 2: LDS-staged MFMA flash attention ----------------
// 128 q/block, q split across 4 waves; K/V 64-key tiles double-buffered in
// LDS, reg-staged one tile ahead (R11 lesson: per-wave KV gathers are
// TA-request bound; block-shared staging cuts requests ~6x).
#define KROW 40   // 32 d + 8 pad (f16) -> 80 B rows, b128-clean
#define VROW 72   // 64 keys + 8 pad   -> 144 B rows, b64-clean

struct KV32 {
    f16x8 k0, k1;
    f16x4 v0n0, v0n1, v1n0, v1n1;
};

__device__ __forceinline__ KV32 lds_frags(const f16* kl, const f16* vl,
                                          int jb, int col, int quad) {
    KV32 f;
    f.k0 = *(const f16x8*)(kl + (jb + col) * KROW + quad * 8);
    f.k1 = *(const f16x8*)(kl + (jb + 16 + col) * KROW + quad * 8);
    f.v0n0 = *(const f16x4*)(vl + col * VROW + jb + quad * 4);
    f.v0n1 = *(const f16x4*)(vl + (16 + col) * VROW + jb + quad * 4);
    f.v1n0 = *(const f16x4*)(vl + col * VROW + jb + 16 + quad * 4);
    f.v1n1 = *(const f16x4*)(vl + (16 + col) * VROW + jb + 16 + quad * 4);
    return f;
}

__device__ __forceinline__ f16x4 expblk(f32x4 s, float& lacc) {
    float p0 = EXP2F(s[0]), p1 = EXP2F(s[1]);
    float p2 = EXP2F(s[2]), p3 = EXP2F(s[3]);
    lacc += (p0 + p1) + (p2 + p3);
    f16x4 r;
    r[0] = (f16)p0; r[1] = (f16)p1; r[2] = (f16)p2; r[3] = (f16)p3;
    return r;
}

__device__ __forceinline__ void compute32(const KV32& f, f16x8 qB0, f16x8 qB1,
                                          f32x4& o00, f32x4& o01,
                                          f32x4& o10, f32x4& o11,
                                          float& l0, float& l1) {
    const f32x4 zs = {-NSHIFT, -NSHIFT, -NSHIFT, -NSHIFT};
    f32x4 s00 = __builtin_amdgcn_mfma_f32_16x16x32_f16(f.k0, qB0, zs, 0, 0, 0);
    f32x4 s10 = __builtin_amdgcn_mfma_f32_16x16x32_f16(f.k0, qB1, zs, 0, 0, 0);
    f32x4 s01 = __builtin_amdgcn_mfma_f32_16x16x32_f16(f.k1, qB0, zs, 0, 0, 0);
    f32x4 s11 = __builtin_amdgcn_mfma_f32_16x16x32_f16(f.k1, qB1, zs, 0, 0, 0);
    f16x4 p00 = expblk(s00, l0);
    f16x4 p10 = expblk(s10, l1);
    f16x4 p01 = expblk(s01, l0);
    f16x4 p11 = expblk(s11, l1);
    o00 = __builtin_amdgcn_mfma_f32_16x16x16f16(p00, f.v0n0, o00, 0, 0, 0);
    o01 = __builtin_amdgcn_mfma_f32_16x16x16f16(p00, f.v0n1, o01, 0, 0, 0);
    o10 = __builtin_amdgcn_mfma_f32_16x16x16f16(p10, f.v0n0, o10, 0, 0, 0);
    o11 = __builtin_amdgcn_mfma_f32_16x16x16f16(p10, f.v0n1, o11, 0, 0, 0);
    o00 = __builtin_amdgcn_mfma_f32_16x16x16f16(p01, f.v1n0, o00, 0, 0, 0);
    o01 = __builtin_amdgcn_mfma_f32_16x16x16f16(p01, f.v1n1, o01, 0, 0, 0);
    o10 = __builtin_amdgcn_mfma_f32_16x16x16f16(p11, f.v1n0, o10, 0, 0, 0);
    o11 = __builtin_amdgcn_mfma_f32_16x16x16f16(p11, f.v1n1, o11, 0, 0, 0);
}

__global__ __launch_bounds__(256, 4) void attn_mfma(const f16* __restrict__ qh,
                                                    const f16* __restrict__ kh,
                                                    const f16* __restrict__ vh,
                                                    f16* __restrict__ att16) {
    __shared__ __align__(16) f16 klds[2][64 * KROW];
    __shared__ __align__(16) f16 vlds[2][32 * VROW];
    int t = threadIdx.x;
    int wave = t >> 6, lane = t & 63;
    int quad = lane >> 4, col = lane & 15;

    // 512 blocks; bid&7 grouping (2 bh per XCD, K/V L2-resident — R10-proven).
    int bid = blockIdx.x;
    int xcd = bid & 7;
    int slot = bid >> 3;             // 0..63
    int bh = xcd * 2 + (slot >> 5);  // 0..15
    int i0 = (slot & 31) * 128;
    int iw = i0 + wave * 32;

    const f16* qb = qh + (size_t)bh * NN * 32;
    const f16* kb = kh + (size_t)bh * NN * 32;
    const f16* vb = vh + (size_t)bh * 32 * NN;

    f16x8 qB0 = *(const f16x8*)(qb + (size_t)(iw + col) * 32 + quad * 8);
    f16x8 qB1 = *(const f16x8*)(qb + (size_t)(iw + 16 + col) * 32 + quad * 8);

    f32x4 o00 = {0.f, 0.f, 0.f, 0.f}, o01 = o00, o10 = o00, o11 = o00;
    float l0 = 0.f, l1 = 0.f;

    // staging helpers (256 threads: K 64x32 in 16B segs, V 32x64 in 16B segs)
    int ktr = t >> 2, kts = t & 3;
    int vtr = t >> 3, vts = t & 7;

    f16x8 kr, vr;
    // tile 0: load + write + barrier
    kr = *(const f16x8*)(kb + (size_t)(0 + ktr) * 32 + kts * 8);
    vr = *(const f16x8*)(vb + (size_t)vtr * NN + 0 + vts * 8);
    *(f16x8*)(&klds[0][0] + ktr * KROW + kts * 8) = kr;
    *(f16x8*)(&vlds[0][0] + vtr * VROW + vts * 8) = vr;
    __syncthreads();
    // prefetch tile 1 into regs
    kr = *(const f16x8*)(kb + (size_t)(64 + ktr) * 32 + kts * 8);
    vr = *(const f16x8*)(vb + (size_t)vtr * NN + 64 + vts * 8);

    for (int tile = 0; tile < 62; tile++) {
        int buf = tile & 1;
        const f16* kl = &klds[buf][0];
        const f16* vl = &vlds[buf][0];
        KV32 f0 = lds_frags(kl, vl, 0, col, quad);
        KV32 f1 = lds_frags(kl, vl, 32, col, quad);
        compute32(f0, qB0, qB1, o00, o01, o10, o11, l0, l1);
        compute32(f1, qB0, qB1, o00, o01, o10, o11, l0, l1);
        *(f16x8*)(&klds[buf ^ 1][0] + ktr * KROW + kts * 8) = kr;
        *(f16x8*)(&vlds[buf ^ 1][0] + vtr * VROW + vts * 8) = vr;
        __syncthreads();
        int j0 = (tile + 2) * 64;
        kr = *(const f16x8*)(kb + (size_t)(j0 + ktr) * 32 + kts * 8);
        vr = *(const f16x8*)(vb + (size_t)vtr * NN + j0 + vts * 8);
    }
    {   // tile 62 (buf 0); kr/vr hold tile 63
        KV32 f0 = lds_frags(&klds[0][0], &vlds[0][0], 0, col, quad);
        KV32 f1 = lds_frags(&klds[0][0], &vlds[0][0], 32, col, quad);
        compute32(f0, qB0, qB1, o00, o01, o10, o11, l0, l1);
        compute32(f1, qB0, qB1, o00, o01, o10, o11, l0, l1);
        *(f16x8*)(&klds[1][0] + ktr * KROW + kts * 8) = kr;
        *(f16x8*)(&vlds[1][0] + vtr * VROW + vts * 8) = vr;
        __syncthreads();
    }
    {   // tile 63 (buf 1)
        KV32 f0 = lds_frags(&klds[1][0], &vlds[1][0], 0, col, quad);
        KV32 f1 = lds_frags(&klds[1][0], &vlds[1][0], 32, col, quad);
        compute32(f0, qB0, qB1, o00, o01, o10, o11, l0, l1);
        compute32(f1, qB0, qB1, o00, o01, o10, o11, l0, l1);
    }

    // full l per q (q = col): reduce across quads
    l0 += __shfl_xor(l0, 16); l0 += __shfl_xor(l0, 32);
    l1 += __shfl_xor(l1, 16); l1 += __shfl_xor(l1, 32);

    // wave-local epilogue: O row = q = quad*4+r, col = dh. Store f16 i-major.
    int b = bh >> 2, h = bh & 3;
    f16* ab = att16 + (size_t)b * NN * HID + h * 32;
#pragma unroll
    for (int r = 0; r < 4; r++) {
        float inv0 = __builtin_amdgcn_rcpf(__shfl(l0, quad * 4 + r));
        float inv1 = __builtin_amdgcn_rcpf(__shfl(l1, quad * 4 + r));
        size_t row0 = (size_t)(iw + quad * 4 + r) * HID;
        size_t row1 = (size_t)(iw + 16 + quad * 4 + r) * HID;
        ab[row0 + col]      = (f16)(o00[r] * inv0);
        ab[row0 + 16 + col] = (f16)(o01[r] * inv0);
        ab[row1 + col]      = (f16)(o10[r] * inv1);
        ab[row1 + 16 + col] = (f16)(o11[r] * inv1);
    }
}

// ---------------- kernel 3: output projection (MFMA) + bias ----------------
__global__ __launch_bounds__(256) void out_mfma(const f16* __restrict__ att16,
                                                const float* __restrict__ wo,
                                                const float* __restrict__ bo,
                                                float* __restrict__ out) {
    int wave = threadIdx.x >> 6, lane = threadIdx.x & 63;
    int quad = lane >> 4, col = lane & 15;
    int b = blockIdx.z;
    int i0 = (blockIdx.x * 4 + wave) * 32;
    int o0 = blockIdx.y * 64;
    const f16* ab = att16 + (size_t)b * NN * HID;

    const f32x4 z = {0.f, 0.f, 0.f, 0.f};
    f32x4 c[2][4];
#pragma unroll
    for (int it = 0; it < 2; it++)
#pragma unroll
        for (int ot = 0; ot < 4; ot++) c[it][ot] = z;

#pragma unroll
    for (int k0 = 0; k0 < HID; k0 += 32) {
        f16x8 a0 = *(const f16x8*)(ab + (size_t)(i0 + col) * HID + k0 + quad * 8);
        f16x8 a1 = *(const f16x8*)(ab + (size_t)(i0 + 16 + col) * HID + k0 + quad * 8);
#pragma unroll
        for (int ot = 0; ot < 4; ot++) {
            f16x8 bf = cvt8(wo + (size_t)(o0 + ot * 16 + col) * HID + k0 + quad * 8);
            c[0][ot] = __builtin_amdgcn_mfma_f32_16x16x32_f16(a0, bf, c[0][ot], 0, 0, 0);
            c[1][ot] = __builtin_amdgcn_mfma_f32_16x16x32_f16(a1, bf, c[1][ot], 0, 0, 0);
        }
    }

#pragma unroll
    for (int it = 0; it < 2; it++)
#pragma unroll
        for (int ot = 0; ot < 4; ot++) {
            int o = o0 + ot * 16 + col;
            float bias = bo[o];
            int i = i0 + it * 16 + quad * 4;
            float4 st = {c[it][ot][0] + bias, c[it][ot][1] + bias,
                         c[it][ot][2] + bias, c[it][ot][3] + bias};
            *(float4*)(out + ((size_t)b * CC + o) * NN + i) = st;
        }
}

extern "C" void kernel_launch(void* const* d_in, const int* in_sizes, int n_in,
                              void* d_out, int out_size, void* d_ws, size_t ws_size,
                              hipStream_t stream) {
    const float* x     = (const float*)d_in[0];
    const float* w_qkv = (const float*)d_in[1];
    const float* w_out = (const float*)d_in[2];
    const float* b_out = (const float*)d_in[3];
    float* out = (float*)d_out;

    char* ws = (char*)d_ws;
    f16* qh    = (f16*)(ws);                        // 4 MB
    f16* kh    = (f16*)(ws + (4u << 20));           // 4 MB
    f16* vh    = (f16*)(ws + (8u << 20));           // 4 MB
    f16* att16 = (f16*)(ws + (12u << 20));          // 4 MB

    qkv_fused<<<dim3(NN / 128, 384 / 64, BB), 256, 0, stream>>>(x, w_qkv, qh, kh, vh);
    attn_mfma<<<dim3(512), 256, 0, stream>>>(qh, kh, vh, att16);
    out_mfma<<<dim3(NN / 128, CC / 64, BB), 256, 0, stream>>>(att16, w_out, b_out, out);
}